// Round 1
// baseline (451.562 us; speedup 1.0000x reference)
//
#include <hip/hip_runtime.h>
#include <hip/hip_bf16.h>

#define NN 100000
#define EE 1600000
#define RR 8
#define DD 64
#define MM (NN * RR)                 // 800000 (dst,rel) segments
#define BN_EPS 1e-5f
#define KTOT 576                     // 512 (rel) + 64 (root)
#define BSTRIDE 584                  // LDS A row pitch in shorts (292 words % 32 = 4)

// bucket sort params: 256 dsts per bucket -> 2048 (dst,rel) keys per bucket
#define NB 391                       // ceil(100000/256)
#define EPB 8192                     // edges per block in binning kernels
#define NBIN ((EE + EPB - 1) / EPB)  // 196

typedef __bf16 bf16x8 __attribute__((ext_vector_type(8)));
typedef float  f32x4  __attribute__((ext_vector_type(4)));

static __device__ __forceinline__ unsigned short f32_to_bf16(float f) {
    unsigned int u = __float_as_uint(f);
    unsigned int r = u + 0x7FFFu + ((u >> 16) & 1u);   // RNE
    return (unsigned short)(r >> 16);
}
static __device__ __forceinline__ float bflo(unsigned int u) {
    return __uint_as_float(u << 16);
}
static __device__ __forceinline__ float bfhi(unsigned int u) {
    return __uint_as_float(u & 0xFFFF0000u);
}

// ---------------- bucketed CSR build ----------------

__global__ void k_bcount(const int* __restrict__ dst, int* __restrict__ btot) {
    __shared__ int cnt[NB];
    int t = threadIdx.x;
    for (int i = t; i < NB; i += 256) cnt[i] = 0;
    __syncthreads();
    int base = blockIdx.x * EPB;
#pragma unroll
    for (int i = 0; i < EPB / 256; ++i) {
        int e = base + i * 256 + t;
        if (e < EE) atomicAdd(&cnt[dst[e] >> 8], 1);
    }
    __syncthreads();
    for (int i = t; i < NB; i += 256)
        if (cnt[i]) atomicAdd(&btot[i], cnt[i]);
}

__global__ void k_bscan(const int* __restrict__ btot, int* __restrict__ bbase,
                        int* __restrict__ gcur, int* __restrict__ rowptr) {
    __shared__ int sd[512];
    int t = threadIdx.x;
    int v = (t < NB) ? btot[t] : 0;
    sd[t] = v;
    __syncthreads();
    for (int off = 1; off < 512; off <<= 1) {
        int x = (t >= off) ? sd[t - off] : 0;
        __syncthreads();
        sd[t] += x;
        __syncthreads();
    }
    if (t < NB) { bbase[t] = sd[t] - v; gcur[t] = sd[t] - v; }
    if (t == NB - 1) { bbase[NB] = sd[t]; rowptr[MM] = sd[t]; }
}

// bin edges into bucket-contiguous ebuf, packed: src | (localkey << 17)
__global__ void k_bin(const int* __restrict__ src, const int* __restrict__ dst,
                      const int* __restrict__ et, int* __restrict__ gcur,
                      unsigned int* __restrict__ ebuf) {
    __shared__ int cnt[NB];
    __shared__ int bas[NB];
    __shared__ int off[NB];
    int t = threadIdx.x;
    for (int i = t; i < NB; i += 256) { cnt[i] = 0; off[i] = 0; }
    __syncthreads();
    int base = blockIdx.x * EPB;
#pragma unroll
    for (int i = 0; i < EPB / 256; ++i) {
        int e = base + i * 256 + t;
        if (e < EE) atomicAdd(&cnt[dst[e] >> 8], 1);
    }
    __syncthreads();
    for (int i = t; i < NB; i += 256) {
        int c = cnt[i];
        bas[i] = c ? atomicAdd(&gcur[i], c) : 0;
    }
    __syncthreads();
#pragma unroll
    for (int i = 0; i < EPB / 256; ++i) {
        int e = base + i * 256 + t;
        if (e < EE) {
            int d = dst[e];
            int b = d >> 8;
            int lk = ((d & 255) << 3) | et[e];
            unsigned int rec0 = (unsigned int)src[e] | ((unsigned int)lk << 17);
            int p = bas[b] + atomicAdd(&off[b], 1);
            ebuf[p] = rec0;
        }
    }
}

// per-bucket: LDS histogram + scan -> rowptr; LDS cursors -> sorted rec
__global__ __launch_bounds__(256) void k_bcsr(const int* __restrict__ bbase,
                                              const unsigned int* __restrict__ ebuf,
                                              int* __restrict__ rowptr,
                                              int* __restrict__ rec) {
    __shared__ int deg[2048];
    __shared__ int part[256];
    int b = blockIdx.x, t = threadIdx.x;
    int e0 = bbase[b], e1 = bbase[b + 1];
    for (int i = t; i < 2048; i += 256) deg[i] = 0;
    __syncthreads();
    for (int e = e0 + t; e < e1; e += 256) atomicAdd(&deg[ebuf[e] >> 17], 1);
    __syncthreads();
    int loc[8];
    int s = 0;
#pragma unroll
    for (int j = 0; j < 8; ++j) { loc[j] = deg[t * 8 + j]; s += loc[j]; }
    part[t] = s;
    __syncthreads();
    for (int off = 1; off < 256; off <<= 1) {
        int x = (t >= off) ? part[t - off] : 0;
        __syncthreads();
        part[t] += x;
        __syncthreads();
    }
    int run = part[t] - s;
    int keyBase = b * 2048;
#pragma unroll
    for (int j = 0; j < 8; ++j) {
        int g = keyBase + t * 8 + j;
        if (g < MM) rowptr[g] = e0 + run;
        deg[t * 8 + j] = run;
        run += loc[j];
    }
    __syncthreads();
    for (int e = e0 + t; e < e1; e += 256) {
        unsigned int v = ebuf[e];
        int lk = v >> 17;
        int pos = e0 + atomicAdd(&deg[lk], 1);
        rec[pos] = (int)(v & 0x1FFFFu);
    }
}

// ---------------- fp32 -> bf16 row conversion ----------------

__global__ void k_tobf16(const float* __restrict__ X, unsigned short* __restrict__ Xb) {
    int i = blockIdx.x * 256 + threadIdx.x;
    if (i >= NN * DD / 4) return;
    float4 v = ((const float4*)X)[i];
    ushort4 o;
    o.x = f32_to_bf16(v.x); o.y = f32_to_bf16(v.y);
    o.z = f32_to_bf16(v.z); o.w = f32_to_bf16(v.w);
    ((ushort4*)Xb)[i] = o;
}

// ---------------- weight prep: WcT[64][576] bf16, k = r*64+d (+root tail) ----------------

__global__ void k_prepw(const float* __restrict__ W, const float* __restrict__ Root,
                        unsigned short* __restrict__ WcT) {
    int i = blockIdx.x * 256 + threadIdx.x;
    if (i >= 64 * KTOT) return;
    int o = i / KTOT;
    int k = i - o * KTOT;
    float v;
    if (k < 512) v = W[(size_t)(k >> 6) * 4096 + (k & 63) * 64 + o];
    else         v = Root[(k - 512) * 64 + o];
    WcT[(size_t)o * KTOT + k] = f32_to_bf16(v);
}

// ---------------- fused aggregate + MFMA GEMM ----------------
// Block = 256 threads = 4 waves = 32 nodes (NN % 32 == 0 -> 3125 blocks).
// Phase 1: wave wv aggregates nodes [base+wv*8, base+wv*8+8); lane l holds
//   dims [8l, 8l+8) of the 512-wide per-(n,r) mean row -> packed bf16 row
//   written to LDS A-tile [32][BSTRIDE]; Xb root row appended at k=512.
// Phase 2: 18x k-blocks of mfma_f32_16x16x32_bf16; A from LDS, B-frags read
//   straight from L2-resident WcT (73 KB, shared by all blocks).
// Optional fused column stats (sum, sumsq) for BN.

__global__ __launch_bounds__(256, 4) void k_fused(const unsigned short* __restrict__ Xb,
                                                  const int* __restrict__ rowptr,
                                                  const int* __restrict__ rec,
                                                  const unsigned short* __restrict__ WcT,
                                                  const float* __restrict__ bias,
                                                  float* __restrict__ Out,
                                                  float* __restrict__ stats,
                                                  int dostats) {
    __shared__ unsigned short Atile[32 * BSTRIDE];   // 36.5 KB
    __shared__ float ssum[4][32];
    __shared__ float ssq[4][32];
    int t = threadIdx.x;
    int wv = t >> 6, lane = t & 63;
    int r = lane >> 3;       // segment 0..7
    int q = lane & 7;        // dim-octet 0..7
    int nodeBase = blockIdx.x * 32 + wv * 8;
    int base8 = nodeBase * RR;
    // coalesced rowptr prefetch for all 8 nodes of this wave
    int v0 = rowptr[base8 + lane];
    int v1 = rowptr[base8 + lane + 1];

    // root tail: lane (i=lane>>3, c=lane&7) copies Xb[node i] chunk c -> k=512..575
    {
        int i = lane >> 3, c = lane & 7;
        uint4 xv = *(const uint4*)(Xb + (size_t)(nodeBase + i) * DD + c * 8);
        *(uint4*)(Atile + (size_t)(wv * 8 + i) * BSTRIDE + 512 + c * 8) = xv;
    }

#pragma unroll 1
    for (int i = 0; i < 8; ++i) {
        int e0 = __shfl(v0, i * 8 + r);
        int e1 = __shfl(v1, i * 8 + r);
        float a0[8] = {0,0,0,0,0,0,0,0};
        float a1[8] = {0,0,0,0,0,0,0,0};
        float a2[8] = {0,0,0,0,0,0,0,0};
        float a3[8] = {0,0,0,0,0,0,0,0};
        int e = e0;
        for (; e + 3 < e1; e += 4) {
            int s0 = rec[e], s1 = rec[e + 1], s2 = rec[e + 2], s3 = rec[e + 3];
            uint4 u0 = *(const uint4*)(Xb + (size_t)s0 * DD + q * 8);
            uint4 u1 = *(const uint4*)(Xb + (size_t)s1 * DD + q * 8);
            uint4 u2 = *(const uint4*)(Xb + (size_t)s2 * DD + q * 8);
            uint4 u3 = *(const uint4*)(Xb + (size_t)s3 * DD + q * 8);
            a0[0] += bflo(u0.x); a0[1] += bfhi(u0.x); a0[2] += bflo(u0.y); a0[3] += bfhi(u0.y);
            a0[4] += bflo(u0.z); a0[5] += bfhi(u0.z); a0[6] += bflo(u0.w); a0[7] += bfhi(u0.w);
            a1[0] += bflo(u1.x); a1[1] += bfhi(u1.x); a1[2] += bflo(u1.y); a1[3] += bfhi(u1.y);
            a1[4] += bflo(u1.z); a1[5] += bfhi(u1.z); a1[6] += bflo(u1.w); a1[7] += bfhi(u1.w);
            a2[0] += bflo(u2.x); a2[1] += bfhi(u2.x); a2[2] += bflo(u2.y); a2[3] += bfhi(u2.y);
            a2[4] += bflo(u2.z); a2[5] += bfhi(u2.z); a2[6] += bflo(u2.w); a2[7] += bfhi(u2.w);
            a3[0] += bflo(u3.x); a3[1] += bfhi(u3.x); a3[2] += bflo(u3.y); a3[3] += bfhi(u3.y);
            a3[4] += bflo(u3.z); a3[5] += bfhi(u3.z); a3[6] += bflo(u3.w); a3[7] += bfhi(u3.w);
        }
        if (e + 1 < e1) {
            int s0 = rec[e], s1 = rec[e + 1];
            uint4 u0 = *(const uint4*)(Xb + (size_t)s0 * DD + q * 8);
            uint4 u1 = *(const uint4*)(Xb + (size_t)s1 * DD + q * 8);
            a0[0] += bflo(u0.x); a0[1] += bfhi(u0.x); a0[2] += bflo(u0.y); a0[3] += bfhi(u0.y);
            a0[4] += bflo(u0.z); a0[5] += bfhi(u0.z); a0[6] += bflo(u0.w); a0[7] += bfhi(u0.w);
            a1[0] += bflo(u1.x); a1[1] += bfhi(u1.x); a1[2] += bflo(u1.y); a1[3] += bfhi(u1.y);
            a1[4] += bflo(u1.z); a1[5] += bfhi(u1.z); a1[6] += bflo(u1.w); a1[7] += bfhi(u1.w);
            e += 2;
        }
        if (e < e1) {
            int s0 = rec[e];
            uint4 u0 = *(const uint4*)(Xb + (size_t)s0 * DD + q * 8);
            a0[0] += bflo(u0.x); a0[1] += bfhi(u0.x); a0[2] += bflo(u0.y); a0[3] += bfhi(u0.y);
            a0[4] += bflo(u0.z); a0[5] += bfhi(u0.z); a0[6] += bflo(u0.w); a0[7] += bfhi(u0.w);
        }
        int cnt = e1 - e0;
        float inv = 1.0f / (float)(cnt > 1 ? cnt : 1);
        uint4 o;
        o.x = (unsigned)f32_to_bf16((a0[0]+a1[0]+a2[0]+a3[0]) * inv) | ((unsigned)f32_to_bf16((a0[1]+a1[1]+a2[1]+a3[1]) * inv) << 16);
        o.y = (unsigned)f32_to_bf16((a0[2]+a1[2]+a2[2]+a3[2]) * inv) | ((unsigned)f32_to_bf16((a0[3]+a1[3]+a2[3]+a3[3]) * inv) << 16);
        o.z = (unsigned)f32_to_bf16((a0[4]+a1[4]+a2[4]+a3[4]) * inv) | ((unsigned)f32_to_bf16((a0[5]+a1[5]+a2[5]+a3[5]) * inv) << 16);
        o.w = (unsigned)f32_to_bf16((a0[6]+a1[6]+a2[6]+a3[6]) * inv) | ((unsigned)f32_to_bf16((a0[7]+a1[7]+a2[7]+a3[7]) * inv) << 16);
        *(uint4*)(Atile + (size_t)(wv * 8 + i) * BSTRIDE + lane * 8) = o;
    }
    __syncthreads();

    // ---- phase 2: GEMM. wave wv -> row-tile rt=wv>>1 (16 rows), col-half ch=wv&1 (32 cols)
    int m16 = lane & 15, quad = lane >> 4;
    int rt = wv >> 1, ch = wv & 1;
    const unsigned short* as = Atile + (rt * 16 + m16) * BSTRIDE + quad * 8;
    const unsigned short* bg = WcT + (size_t)(ch * 32 + m16) * KTOT + quad * 8;
    union AU { uint4 u; bf16x8 f; };
    f32x4 acc[2];
    acc[0] = (f32x4){0.f, 0.f, 0.f, 0.f};
    acc[1] = (f32x4){0.f, 0.f, 0.f, 0.f};
#pragma unroll
    for (int kb = 0; kb < 18; ++kb) {
        AU av, b0, b1;
        av.u = *(const uint4*)(as + kb * 32);
        b0.u = *(const uint4*)(bg + kb * 32);
        b1.u = *(const uint4*)(bg + 16 * KTOT + kb * 32);
        acc[0] = __builtin_amdgcn_mfma_f32_16x16x32_bf16(av.f, b0.f, acc[0], 0, 0, 0);
        acc[1] = __builtin_amdgcn_mfma_f32_16x16x32_bf16(av.f, b1.f, acc[1], 0, 0, 0);
    }

    int row0 = blockIdx.x * 32 + rt * 16 + quad * 4;
#pragma unroll
    for (int nt = 0; nt < 2; ++nt) {
        int col = ch * 32 + nt * 16 + m16;
        float bb = bias[col];
        float s = 0.f, sq = 0.f;
#pragma unroll
        for (int i2 = 0; i2 < 4; ++i2) {
            float v = acc[nt][i2] + bb;
            Out[(size_t)(row0 + i2) * 64 + col] = v;
            s += v; sq += v * v;
        }
        if (dostats) {
            s += __shfl_xor(s, 16); s += __shfl_xor(s, 32);
            sq += __shfl_xor(sq, 16); sq += __shfl_xor(sq, 32);
            if (quad == 0) { ssum[wv][nt * 16 + m16] = s; ssq[wv][nt * 16 + m16] = sq; }
        }
    }
    if (dostats) {
        __syncthreads();
        if (t < 64) {
            int half = t >> 5, cl = t & 31;
            atomicAdd(&stats[t], ssum[half][cl] + ssum[half + 2][cl]);
        } else if (t < 128) {
            int c2 = t - 64;
            int half = c2 >> 5, cl = c2 & 31;
            atomicAdd(&stats[64 + c2], ssq[half][cl] + ssq[half + 2][cl]);
        }
    }
}

// ---------------- BN+ReLU (read fp32 H, write bf16 Hb only) ----------------

__global__ void k_bnrelu(const float* __restrict__ H, unsigned short* __restrict__ Hb,
                         const float* __restrict__ stats,
                         const float* __restrict__ gamma, const float* __restrict__ beta) {
    int idx = blockIdx.x * 256 + threadIdx.x;
    const int total = NN * DD / 4;
    if (idx >= total) return;
    int c0 = (idx & 15) * 4;
    float4 v = ((const float4*)H)[idx];
    float inv = 1.0f / (float)NN;
    float4 o;
    {
        float mu = stats[c0 + 0] * inv;
        float var = stats[64 + c0 + 0] * inv - mu * mu;
        float sc = gamma[c0 + 0] * rsqrtf(var + BN_EPS);
        float r = sc * (v.x - mu) + beta[c0 + 0];
        o.x = r > 0.f ? r : 0.f;
    }
    {
        float mu = stats[c0 + 1] * inv;
        float var = stats[64 + c0 + 1] * inv - mu * mu;
        float sc = gamma[c0 + 1] * rsqrtf(var + BN_EPS);
        float r = sc * (v.y - mu) + beta[c0 + 1];
        o.y = r > 0.f ? r : 0.f;
    }
    {
        float mu = stats[c0 + 2] * inv;
        float var = stats[64 + c0 + 2] * inv - mu * mu;
        float sc = gamma[c0 + 2] * rsqrtf(var + BN_EPS);
        float r = sc * (v.z - mu) + beta[c0 + 2];
        o.z = r > 0.f ? r : 0.f;
    }
    {
        float mu = stats[c0 + 3] * inv;
        float var = stats[64 + c0 + 3] * inv - mu * mu;
        float sc = gamma[c0 + 3] * rsqrtf(var + BN_EPS);
        float r = sc * (v.w - mu) + beta[c0 + 3];
        o.w = r > 0.f ? r : 0.f;
    }
    ushort4 ob;
    ob.x = f32_to_bf16(o.x); ob.y = f32_to_bf16(o.y);
    ob.z = f32_to_bf16(o.z); ob.w = f32_to_bf16(o.w);
    ((ushort4*)Hb)[idx] = ob;
}

// ---------------- launch ----------------

static inline size_t alignup(size_t x) { return (x + 255) & ~(size_t)255; }

extern "C" void kernel_launch(void* const* d_in, const int* in_sizes, int n_in,
                              void* d_out, int out_size, void* d_ws, size_t ws_size,
                              hipStream_t stream) {
    const float* x      = (const float*)d_in[0];
    const int*   eidx   = (const int*)d_in[1];
    const int*   etype  = (const int*)d_in[2];
    const float* w1     = (const float*)d_in[3];
    const float* root1  = (const float*)d_in[4];
    const float* b1     = (const float*)d_in[5];
    const float* gamma1 = (const float*)d_in[6];
    const float* beta1  = (const float*)d_in[7];
    const float* w2     = (const float*)d_in[8];
    const float* root2  = (const float*)d_in[9];
    const float* b2     = (const float*)d_in[10];
    float* out = (float*)d_out;

    const int* src = eidx;
    const int* dst = eidx + EE;

    char* w = (char*)d_ws;
    int* rowptr = (int*)w;            w += alignup((size_t)(MM + 1) * 4);
    int* btot   = (int*)w;            w += alignup(512 * 4);
    int* bbase  = (int*)w;            w += alignup(512 * 4);
    int* gcur   = (int*)w;            w += alignup(512 * 4);
    int* rec    = (int*)w;            w += alignup((size_t)EE * 4);
    float* h    = (float*)w;          w += alignup((size_t)NN * DD * 4);
    unsigned short* xhb = (unsigned short*)w; w += alignup((size_t)NN * DD * 2);
    unsigned short* wct1 = (unsigned short*)w; w += alignup((size_t)64 * KTOT * 2);
    unsigned short* wct2 = (unsigned short*)w; w += alignup((size_t)64 * KTOT * 2);
    float* stats = (float*)w;         w += alignup(128 * 4);
    unsigned int* ebuf = (unsigned int*)h;   // alias: ebuf dead before k_fused writes h

    hipMemsetAsync(btot, 0, 512 * 4, stream);
    hipMemsetAsync(stats, 0, 128 * 4, stream);

    k_prepw<<<dim3(144), dim3(256), 0, stream>>>(w1, root1, wct1);
    k_prepw<<<dim3(144), dim3(256), 0, stream>>>(w2, root2, wct2);
    k_tobf16<<<dim3(NN * DD / 4 / 256 + 1), dim3(256), 0, stream>>>(x, xhb);

    // bucketed CSR build
    k_bcount<<<dim3(NBIN), dim3(256), 0, stream>>>(dst, btot);
    k_bscan<<<dim3(1), dim3(512), 0, stream>>>(btot, bbase, gcur, rowptr);
    k_bin<<<dim3(NBIN), dim3(256), 0, stream>>>(src, dst, etype, gcur, ebuf);
    k_bcsr<<<dim3(NB), dim3(256), 0, stream>>>(bbase, ebuf, rowptr, rec);

    // layer 1: fused aggregate+GEMM (with BN column stats)
    k_fused<<<dim3(NN / 32), dim3(256), 0, stream>>>(xhb, rowptr, rec, wct1, b1, h, stats, 1);
    k_bnrelu<<<dim3(NN * DD / 4 / 256), dim3(256), 0, stream>>>(h, xhb, stats, gamma1, beta1);

    // layer 2 (xhb now holds bf16 of post-BN/ReLU h)
    k_fused<<<dim3(NN / 32), dim3(256), 0, stream>>>(xhb, rowptr, rec, wct2, b2, out, stats, 0);
}